// Round 5
// baseline (211.427 us; speedup 1.0000x reference)
//
#include <hip/hip_runtime.h>
#include <stdint.h>

#define BROWS 16384
#define DDIM  512
#define EEXP  16
#define HDIM  256
#define LDIM  64
#define BM    64
#define ZCHUNKS 1024   // out = 4M float4 -> 1024 chunks of 4096 float4 (64 KB)

typedef __bf16  bf16x8  __attribute__((ext_vector_type(8)));
typedef float   floatx4 __attribute__((ext_vector_type(4)));
typedef ushort  ushort8 __attribute__((ext_vector_type(8)));
typedef unsigned int u32;

__device__ __forceinline__ ushort f2bf(float f) {
    uint32_t u = __builtin_bit_cast(uint32_t, f);
    u += 0x7fffu + ((u >> 16) & 1u);   // RNE
    return (ushort)(u >> 16);
}

// tanh(x) = 1 - 2/(exp2(2x*log2e)+1); saturates correctly, rel err ~1e-6.
__device__ __forceinline__ float fast_tanh(float x) {
    float e = __builtin_amdgcn_exp2f(x * 2.8853900817779268f);
    return 1.0f - 2.0f * __builtin_amdgcn_rcpf(e + 1.0f);
}

__device__ __forceinline__ void gl_lds16(const void* g, void* l) {
    __builtin_amdgcn_global_load_lds(
        (const __attribute__((address_space(1))) u32*)g,
        (__attribute__((address_space(3))) u32*)l, 16, 0, 0);
}

// ---------------------------------------------------------------------------
// MERGED kernel. Blocks 0..511: gating (f32 math unchanged) + fused x->bf16
// swizzled cvt + direct atomic rowlist build. Blocks 512..2815: W1/W2
// transpose+cvt. Zero-fill of inactive out slots moved OUT of this kernel
// (now done by the expert kernel's dead blocks -> coalesced + overlapped).
// ---------------------------------------------------------------------------
__global__ __launch_bounds__(256) void gate_aux_kernel(
    const float* __restrict__ x,      // [B][D]
    const float* __restrict__ noise,  // [B][E]
    const float* __restrict__ wg,     // [D][E]
    const float* __restrict__ wn,     // [D][E]
    const float* __restrict__ W1,     // [E][D][H]
    const float* __restrict__ W2,     // [E][H][L]
    float* __restrict__ gates,        // [B][E]
    ushort* __restrict__ xbf,         // [B][D] bf16 swizzled
    ushort* __restrict__ W1T,         // [E][H][D] bf16 swizzled
    ushort* __restrict__ W2T,         // [E][L][H] bf16 linear
    u32* __restrict__ cnt,            // [E] (pre-zeroed)
    u32* __restrict__ rowlist)        // [E][B] unsorted-compact
{
    if (blockIdx.x >= 512) {
        // ---- transpose path ----
        __shared__ float tile[32][33];
        int b = blockIdx.x - 512;
        const float* src; ushort* dst; int R, C, c0, r0, swz, ei;
        if (b < 2048) {
            ei = b >> 7; int rem = b & 127;
            c0 = (rem & 7) * 32; r0 = (rem >> 3) * 32;
            R = DDIM; C = HDIM; swz = 1;
            src = W1; dst = W1T;
        } else {
            b -= 2048;
            ei = b >> 4; int rem = b & 15;
            c0 = (rem & 1) * 32; r0 = (rem >> 1) * 32;
            R = HDIM; C = LDIM; swz = 0;
            src = W2; dst = W2T;
        }
        const int tx = threadIdx.x & 31, ty = threadIdx.x >> 5;
        const float* s = src + (size_t)ei * R * C;
        ushort* d = dst + (size_t)ei * R * C;

        #pragma unroll
        for (int i = 0; i < 4; ++i) {
            int rr = ty + i * 8;
            tile[rr][tx] = s[(size_t)(r0 + rr) * C + c0 + tx];
        }
        __syncthreads();
        #pragma unroll
        for (int i = 0; i < 4; ++i) {
            int cc = ty + i * 8;
            int h = c0 + cc;
            int col = r0 + tx;
            int col2 = col;
            if (swz) {
                int g = (col >> 3) & 7;
                col2 = (col & ~63) | ((g ^ (h & 7)) << 3) | (col & 7);
            }
            d[(size_t)h * R + col2] = f2bf(tile[tx][cc]);
        }
        return;
    }

    // ---- gating path ----
    __shared__ __align__(16) float xs[32 * 132];    // 16.5 KB
    __shared__ __align__(16) float wTg[16 * 132];   // 8.25 KB
    __shared__ __align__(16) float wTn[16 * 132];   // 8.25 KB
    __shared__ u32 lcnt[16];
    __shared__ u32 lbase[16];
    __shared__ ushort lrows[16 * 32];

    const int t    = threadIdx.x;
    const int blk  = blockIdx.x;
    const int row0 = blk * 32;
    const int og   = t & 15, rg = t >> 4;

    if (t < 16) lcnt[t] = 0;

    floatx4 accg4[2] = {}, accn4[2] = {};

    for (int ch = 0; ch < 4; ++ch) {
        const int k0 = ch * 128;
        __syncthreads();
        {   // stage xs[32][128] + fused bf16 swizzled writeback
            int r = t >> 3, c = (t & 7) * 16;
            const float* src = &x[(size_t)(row0 + r) * DDIM + k0 + c];
            float4 f[4];
            #pragma unroll
            for (int i = 0; i < 4; ++i)
                f[i] = reinterpret_cast<const float4*>(src)[i];
            float* dst = &xs[r * 132 + c];
            #pragma unroll
            for (int i = 0; i < 4; ++i)
                reinterpret_cast<float4*>(dst)[i] = f[i];

            const int row = row0 + r;
            const int sw  = r & 7;
            #pragma unroll
            for (int i = 0; i < 2; ++i) {
                int cb = k0 + c + i * 8;
                int kb = cb >> 6;
                int g  = (cb >> 3) & 7;
                int gp = g ^ sw;
                float4 a = f[i * 2], b = f[i * 2 + 1];
                ushort8 t8;
                t8[0]=f2bf(a.x); t8[1]=f2bf(a.y); t8[2]=f2bf(a.z); t8[3]=f2bf(a.w);
                t8[4]=f2bf(b.x); t8[5]=f2bf(b.y); t8[6]=f2bf(b.z); t8[7]=f2bf(b.w);
                *reinterpret_cast<ushort8*>(&xbf[(size_t)row * DDIM + kb * 64 + gp * 8]) = t8;
            }
        }
        {   // stage wTg/wTn transposed (pad 132 -> conflict-free reads)
            int d = t >> 1, e0 = (t & 1) * 8;
            float4 a0 = *reinterpret_cast<const float4*>(&wg[(size_t)(k0 + d) * EEXP + e0]);
            float4 a1 = *reinterpret_cast<const float4*>(&wg[(size_t)(k0 + d) * EEXP + e0 + 4]);
            float4 b0 = *reinterpret_cast<const float4*>(&wn[(size_t)(k0 + d) * EEXP + e0]);
            float4 b1 = *reinterpret_cast<const float4*>(&wn[(size_t)(k0 + d) * EEXP + e0 + 4]);
            wTg[(e0+0)*132+d]=a0.x; wTg[(e0+1)*132+d]=a0.y; wTg[(e0+2)*132+d]=a0.z; wTg[(e0+3)*132+d]=a0.w;
            wTg[(e0+4)*132+d]=a1.x; wTg[(e0+5)*132+d]=a1.y; wTg[(e0+6)*132+d]=a1.z; wTg[(e0+7)*132+d]=a1.w;
            wTn[(e0+0)*132+d]=b0.x; wTn[(e0+1)*132+d]=b0.y; wTn[(e0+2)*132+d]=b0.z; wTn[(e0+3)*132+d]=b0.w;
            wTn[(e0+4)*132+d]=b1.x; wTn[(e0+5)*132+d]=b1.y; wTn[(e0+6)*132+d]=b1.z; wTn[(e0+7)*132+d]=b1.w;
        }
        __syncthreads();

        #pragma unroll 8
        for (int d4 = 0; d4 < 32; ++d4) {
            floatx4 wgv = *reinterpret_cast<const floatx4*>(&wTg[og * 132 + d4 * 4]);
            floatx4 wnv = *reinterpret_cast<const floatx4*>(&wTn[og * 132 + d4 * 4]);
            #pragma unroll
            for (int rr = 0; rr < 2; ++rr) {
                floatx4 xv = *reinterpret_cast<const floatx4*>(&xs[(rg * 2 + rr) * 132 + d4 * 4]);
                accg4[rr] += xv * wgv;
                accn4[rr] += xv * wnv;
            }
        }
    }

    #pragma unroll
    for (int rr = 0; rr < 2; ++rr) {
        const int row = row0 + rg * 2 + rr;
        float accg = accg4[rr][0] + accg4[rr][1] + accg4[rr][2] + accg4[rr][3];
        float accn = accn4[rr][0] + accn4[rr][1] + accn4[rr][2] + accn4[rr][3];

        // keep libcall-precision softplus: gate threshold flips are the risk
        float sp = fmaxf(accn, 0.f) + log1pf(expf(-fabsf(accn)));
        float stddev = sp + 0.01f;
        float nz = noise[(size_t)row * EEXP + og];
        float z = accg + nz * stddev;

        float m = z;
        #pragma unroll
        for (int mask = 8; mask >= 1; mask >>= 1)
            m = fmaxf(m, __shfl_xor(m, mask, 16));
        float ez = expf(z - m);
        float s = ez;
        #pragma unroll
        for (int mask = 8; mask >= 1; mask >>= 1)
            s += __shfl_xor(s, mask, 16);
        float logit = ez / s;

        float lsum = logit;
        #pragma unroll
        for (int mask = 8; mask >= 1; mask >>= 1)
            lsum += __shfl_xor(lsum, mask, 16);
        float mean = lsum * (1.0f / 16.0f) - 1e-8f;

        float gate = (logit >= mean) ? logit : 0.0f;
        float denom = gate;
        #pragma unroll
        for (int mask = 8; mask >= 1; mask >>= 1)
            denom += __shfl_xor(denom, mask, 16);

        gates[(size_t)row * EEXP + og] = gate / denom;

        if (gate > 0.0f) {
            u32 p = atomicAdd(&lcnt[og], 1u);
            lrows[og * 32 + p] = (ushort)(rg * 2 + rr);
        }
    }

    __syncthreads();
    if (t < 16) lbase[t] = atomicAdd(&cnt[t], lcnt[t]);
    __syncthreads();
    for (int i = t; i < 16 * 32; i += 256) {
        int e = i >> 5, j = i & 31;
        if ((u32)j < lcnt[e])
            rowlist[(size_t)e * BROWS + lbase[e] + j] = row0 + lrows[e * 32 + j];
    }
}

// ---------------------------------------------------------------------------
// Sparse expert MLP, BM=64, 40 KB LDS -> 4 blocks/CU (proven-best structure).
// Block (e,t) processes rowlist[e][t*64 .. +64). DEAD blocks (t*BM >= count)
// do the zero-fill of inactive out slots instead of exiting: coalesced
// float4 stores, chunks via global atomic ticket, fully overlapped with the
// live blocks' MFMA work. Live writes (active slots) and dead writes
// (gates==0 slots) are address-disjoint -> race-free.
// ---------------------------------------------------------------------------
__global__ __launch_bounds__(256, 4) void expert_kernel(
    const ushort* __restrict__ xbf,    // [B][D] bf16, swizzled
    const float*  __restrict__ gates,  // [B][E]
    const ushort* __restrict__ W1T,    // [E][H][D] bf16, swizzled
    const float*  __restrict__ b1,     // [E][H]
    const ushort* __restrict__ W2T,    // [E][L][H] bf16, linear
    const float*  __restrict__ b2,     // [E][L]
    const u32*    __restrict__ cnt,    // [E]
    u32*          __restrict__ zfc,    // zero-fill ticket (pre-zeroed)
    const u32*    __restrict__ rowlist,// [E][B]
    float* __restrict__ out)           // [B][E][L]
{
    __shared__ __align__(16) ushort lds[20480];  // A [0,8K)B, B [8K,40K)B; h [0,32K)B

    const int bx = blockIdx.x;
    const int e  = bx & 15;
    const int t  = bx >> 4;

    const int count = (int)cnt[e];
    const int tid  = threadIdx.x;

    if (t * BM >= count) {
        // ---- zero-fill path (dead block) ----
        __shared__ u32 chunk_s;
        float4* o4 = reinterpret_cast<float4*>(out);
        for (;;) {
            if (tid == 0) chunk_s = atomicAdd(zfc, 1u);
            __syncthreads();
            u32 c = chunk_s;
            __syncthreads();
            if (c >= ZCHUNKS) return;
            const u32 base = c * 4096;   // float4 index; chunk = 64 KB
            #pragma unroll
            for (int k = 0; k < 16; ++k) {
                u32 idx = base + k * 256 + tid;
                u32 slot = idx >> 4;     // one gate per 16 float4
                if (gates[slot] == 0.0f) {
                    float4 z = {0.f, 0.f, 0.f, 0.f};
                    o4[idx] = z;
                }
            }
        }
    }

    const int nrt = min(BM, count - t * BM);
    const u32* rl = rowlist + (size_t)e * BROWS + t * BM;

    const int lane = tid & 63;
    const int wave = tid >> 6;

    const int lr = lane & 15;
    const int q  = lane >> 4;
    const int kq = q * 8;
    const int rq = q * 4;
    const int la = lane >> 3, lb = lane & 7;  // staging lane split

    const char* xg = (const char*)xbf;
    const char* w1 = (const char*)W1T + (size_t)e * HDIM * 1024;

    // Per-lane gathered A-row bases + swizzle re-key terms
    size_t abase[2]; int sxr[2];
    #pragma unroll
    for (int p = 0; p < 2; ++p) {
        int r  = wave * 16 + p * 8 + la;
        int rc = min(r, nrt - 1);
        u32 ri = rl[rc];
        abase[p] = (size_t)ri * 1024;
        sxr[p]   = (la ^ (int)(ri & 7)) << 4;
    }

    floatx4 acc[4][4] = {};

    for (int kb = 0; kb < 8; ++kb) {
        const int koff = kb * 128;   // byte offset within 1024-B row
        #pragma unroll
        for (int p = 0; p < 2; ++p) {   // A tile: 8 KB (gathered rows)
            int c = wave * 2 + p;
            gl_lds16(xg + abase[p] + koff + ((lb << 4) ^ sxr[p]), &lds[c * 512]);
        }
        #pragma unroll
        for (int p = 0; p < 8; ++p) {   // B tile: 32 KB (sequential W1T rows)
            int c = wave * 8 + p;
            gl_lds16(w1 + (size_t)(c * 8 + la) * 1024 + koff + (lb << 4),
                     &lds[4096 + c * 512]);
        }
        __syncthreads();

        #pragma unroll
        for (int s = 0; s < 2; ++s) {
            const int g = s * 4 + q;
            bf16x8 af[4], bfr[4];
            #pragma unroll
            for (int i = 0; i < 4; ++i) {
                int r = i * 16 + lr;
                af[i] = *reinterpret_cast<const bf16x8*>(&lds[r * 64 + ((g ^ (r & 7)) << 3)]);
            }
            #pragma unroll
            for (int j = 0; j < 4; ++j) {
                int r = wave * 64 + j * 16 + lr;
                bfr[j] = *reinterpret_cast<const bf16x8*>(&lds[4096 + r * 64 + ((g ^ (r & 7)) << 3)]);
            }
            #pragma unroll
            for (int i = 0; i < 4; ++i)
                #pragma unroll
                for (int j = 0; j < 4; ++j)
                    acc[i][j] = __builtin_amdgcn_mfma_f32_16x16x32_bf16(
                        af[i], bfr[j], acc[i][j], 0, 0, 0);
        }
        __syncthreads();
    }

    // h = fast_tanh(acc + b1) -> bf16, swizzled [64][256] at lds[0..32K)
    float b1v[4];
    #pragma unroll
    for (int j = 0; j < 4; ++j)
        b1v[j] = b1[e * HDIM + wave * 64 + j * 16 + lr];

    #pragma unroll
    for (int i = 0; i < 4; ++i)
        #pragma unroll
        for (int j = 0; j < 4; ++j) {
            int c = wave * 64 + j * 16 + lr;
            int gg = c >> 3;
            #pragma unroll
            for (int rr = 0; rr < 4; ++rr) {
                int r = i * 16 + rq + rr;
                float v = fast_tanh(acc[i][j][rr] + b1v[j]);
                lds[r * 256 + (((gg & 24) | ((gg & 7) ^ (r & 7))) << 3) + (c & 7)] = f2bf(v);
            }
        }
    __syncthreads();

    // Phase B: y[64][64]; wave owns rows [wave*16,+16); W2 frags from global
    const ushort* w2 = W2T + (size_t)e * LDIM * HDIM;
    floatx4 acc2[4] = {};
    #pragma unroll
    for (int s = 0; s < 8; ++s) {
        int r = wave * 16 + lr;
        int g = s * 4 + q;
        bf16x8 af = *reinterpret_cast<const bf16x8*>(
            &lds[r * 256 + (((g & 24) | ((g & 7) ^ (r & 7))) << 3)]);
        #pragma unroll
        for (int j = 0; j < 4; ++j) {
            bf16x8 bfr = *reinterpret_cast<const bf16x8*>(
                &w2[(size_t)(j * 16 + lr) * HDIM + s * 32 + kq]);
            acc2[j] = __builtin_amdgcn_mfma_f32_16x16x32_bf16(af, bfr, acc2[j], 0, 0, 0);
        }
    }

    float b2v[4];
    #pragma unroll
    for (int j = 0; j < 4; ++j)
        b2v[j] = b2[e * LDIM + j * 16 + lr];

    #pragma unroll
    for (int rr = 0; rr < 4; ++rr) {
        int r  = wave * 16 + rq + rr;
        int rc = min(r, nrt - 1);
        u32 ri = rl[rc];
        float gsc = gates[(size_t)ri * EEXP + e];
        if (r < nrt) {
            #pragma unroll
            for (int j = 0; j < 4; ++j)
                out[(size_t)ri * (EEXP * LDIM) + e * LDIM + j * 16 + lr] =
                    (acc2[j][rr] + b2v[j]) * gsc;
        }
    }
}

// ---------------------------------------------------------------------------
extern "C" void kernel_launch(void* const* d_in, const int* in_sizes, int n_in,
                              void* d_out, int out_size, void* d_ws, size_t ws_size,
                              hipStream_t stream) {
    (void)in_sizes; (void)n_in; (void)out_size; (void)ws_size;
    const float* x     = (const float*)d_in[0];
    const float* noise = (const float*)d_in[1];
    const float* wg    = (const float*)d_in[2];
    const float* wn    = (const float*)d_in[3];
    const float* W1    = (const float*)d_in[4];
    const float* b1    = (const float*)d_in[5];
    const float* W2    = (const float*)d_in[6];
    const float* b2    = (const float*)d_in[7];
    float* out = (float*)d_out;

    char* ws = (char*)d_ws;
    float*  gates   = (float*)ws;                          // 1 MiB
    ushort* W1T     = (ushort*)(ws + (1 << 20));           // 4 MiB
    ushort* W2T     = (ushort*)(ws + (5 << 20));           // 0.5 MiB
    ushort* xbf     = (ushort*)(ws + (6 << 20));           // 16 MiB
    u32*    cnt     = (u32*)(ws + (22 << 20));             // 64 B
    u32*    zfc     = (u32*)(ws + (22 << 20) + 64);        // 4 B ticket
    u32*    rowlist = (u32*)(ws + (24 << 20));             // 1 MiB

    hipMemsetAsync(cnt, 0, 128, stream);   // cnt[16] + zfc
    gate_aux_kernel<<<512 + 2304, 256, 0, stream>>>(
        x, noise, wg, wn, W1, W2, gates, xbf, W1T, W2T, cnt, rowlist);
    expert_kernel<<<(BROWS / BM) * EEXP, 256, 0, stream>>>(
        xbf, gates, W1T, b1, W2T, b2, cnt, zfc, rowlist, out);
}

// Round 6
// 171.939 us; speedup vs baseline: 1.2297x; 1.2297x over previous
//
#include <hip/hip_runtime.h>
#include <stdint.h>

#define BROWS 16384
#define DDIM  512
#define EEXP  16
#define HDIM  256
#define LDIM  64
#define BM    64

typedef __bf16  bf16x8  __attribute__((ext_vector_type(8)));
typedef float   floatx4 __attribute__((ext_vector_type(4)));
typedef ushort  ushort8 __attribute__((ext_vector_type(8)));
typedef unsigned int u32;

__device__ __forceinline__ ushort f2bf(float f) {
    uint32_t u = __builtin_bit_cast(uint32_t, f);
    u += 0x7fffu + ((u >> 16) & 1u);   // RNE
    return (ushort)(u >> 16);
}

// tanh(x) = 1 - 2/(exp2(2x*log2e)+1); saturates correctly, rel err ~1e-6.
__device__ __forceinline__ float fast_tanh(float x) {
    float e = __builtin_amdgcn_exp2f(x * 2.8853900817779268f);
    return 1.0f - 2.0f * __builtin_amdgcn_rcpf(e + 1.0f);
}

__device__ __forceinline__ void gl_lds16(const void* g, void* l) {
    __builtin_amdgcn_global_load_lds(
        (const __attribute__((address_space(1))) u32*)g,
        (__attribute__((address_space(3))) u32*)l, 16, 0, 0);
}

// ---------------------------------------------------------------------------
// MERGED kernel. Blocks 0..511: gating (f32 math unchanged) + fused x->bf16
// swizzled cvt + direct atomic rowlist build + COALESCED zero-fill of
// inactive out slots (LDS inactive-slot list; 16 consecutive threads write
// one 256-B slot -> contiguous segments, vs R3's per-lane 16x16B at 1 KB
// stride). Blocks 512..2815: W1/W2 transpose+cvt.
// ---------------------------------------------------------------------------
__global__ __launch_bounds__(256) void gate_aux_kernel(
    const float* __restrict__ x,      // [B][D]
    const float* __restrict__ noise,  // [B][E]
    const float* __restrict__ wg,     // [D][E]
    const float* __restrict__ wn,     // [D][E]
    const float* __restrict__ W1,     // [E][D][H]
    const float* __restrict__ W2,     // [E][H][L]
    float* __restrict__ gates,        // [B][E]
    ushort* __restrict__ xbf,         // [B][D] bf16 swizzled
    ushort* __restrict__ W1T,         // [E][H][D] bf16 swizzled
    ushort* __restrict__ W2T,         // [E][L][H] bf16 linear
    u32* __restrict__ cnt,            // [E] (pre-zeroed)
    u32* __restrict__ rowlist,        // [E][B] unsorted-compact
    float* __restrict__ out)          // [B][E][L]
{
    if (blockIdx.x >= 512) {
        // ---- transpose path ----
        __shared__ float tile[32][33];
        int b = blockIdx.x - 512;
        const float* src; ushort* dst; int R, C, c0, r0, swz, ei;
        if (b < 2048) {
            ei = b >> 7; int rem = b & 127;
            c0 = (rem & 7) * 32; r0 = (rem >> 3) * 32;
            R = DDIM; C = HDIM; swz = 1;
            src = W1; dst = W1T;
        } else {
            b -= 2048;
            ei = b >> 4; int rem = b & 15;
            c0 = (rem & 1) * 32; r0 = (rem >> 1) * 32;
            R = HDIM; C = LDIM; swz = 0;
            src = W2; dst = W2T;
        }
        const int tx = threadIdx.x & 31, ty = threadIdx.x >> 5;
        const float* s = src + (size_t)ei * R * C;
        ushort* d = dst + (size_t)ei * R * C;

        #pragma unroll
        for (int i = 0; i < 4; ++i) {
            int rr = ty + i * 8;
            tile[rr][tx] = s[(size_t)(r0 + rr) * C + c0 + tx];
        }
        __syncthreads();
        #pragma unroll
        for (int i = 0; i < 4; ++i) {
            int cc = ty + i * 8;
            int h = c0 + cc;
            int col = r0 + tx;
            int col2 = col;
            if (swz) {
                int g = (col >> 3) & 7;
                col2 = (col & ~63) | ((g ^ (h & 7)) << 3) | (col & 7);
            }
            d[(size_t)h * R + col2] = f2bf(tile[tx][cc]);
        }
        return;
    }

    // ---- gating path ----
    __shared__ __align__(16) float xs[32 * 132];    // 16.5 KB
    __shared__ __align__(16) float wTg[16 * 132];   // 8.25 KB
    __shared__ __align__(16) float wTn[16 * 132];   // 8.25 KB
    __shared__ u32 lcnt[16];
    __shared__ u32 lbase[16];
    __shared__ ushort lrows[16 * 32];
    __shared__ u32 izn;                 // inactive-slot count
    __shared__ ushort izlist[512];      // inactive slots: row_local*16+e

    const int t    = threadIdx.x;
    const int blk  = blockIdx.x;
    const int row0 = blk * 32;
    const int og   = t & 15, rg = t >> 4;

    if (t < 16) lcnt[t] = 0;
    if (t == 0) izn = 0;

    floatx4 accg4[2] = {}, accn4[2] = {};

    for (int ch = 0; ch < 4; ++ch) {
        const int k0 = ch * 128;
        __syncthreads();
        {   // stage xs[32][128] + fused bf16 swizzled writeback
            int r = t >> 3, c = (t & 7) * 16;
            const float* src = &x[(size_t)(row0 + r) * DDIM + k0 + c];
            float4 f[4];
            #pragma unroll
            for (int i = 0; i < 4; ++i)
                f[i] = reinterpret_cast<const float4*>(src)[i];
            float* dst = &xs[r * 132 + c];
            #pragma unroll
            for (int i = 0; i < 4; ++i)
                reinterpret_cast<float4*>(dst)[i] = f[i];

            const int row = row0 + r;
            const int sw  = r & 7;
            #pragma unroll
            for (int i = 0; i < 2; ++i) {
                int cb = k0 + c + i * 8;
                int kb = cb >> 6;
                int g  = (cb >> 3) & 7;
                int gp = g ^ sw;
                float4 a = f[i * 2], b = f[i * 2 + 1];
                ushort8 t8;
                t8[0]=f2bf(a.x); t8[1]=f2bf(a.y); t8[2]=f2bf(a.z); t8[3]=f2bf(a.w);
                t8[4]=f2bf(b.x); t8[5]=f2bf(b.y); t8[6]=f2bf(b.z); t8[7]=f2bf(b.w);
                *reinterpret_cast<ushort8*>(&xbf[(size_t)row * DDIM + kb * 64 + gp * 8]) = t8;
            }
        }
        {   // stage wTg/wTn transposed (pad 132 -> conflict-free reads)
            int d = t >> 1, e0 = (t & 1) * 8;
            float4 a0 = *reinterpret_cast<const float4*>(&wg[(size_t)(k0 + d) * EEXP + e0]);
            float4 a1 = *reinterpret_cast<const float4*>(&wg[(size_t)(k0 + d) * EEXP + e0 + 4]);
            float4 b0 = *reinterpret_cast<const float4*>(&wn[(size_t)(k0 + d) * EEXP + e0]);
            float4 b1 = *reinterpret_cast<const float4*>(&wn[(size_t)(k0 + d) * EEXP + e0 + 4]);
            wTg[(e0+0)*132+d]=a0.x; wTg[(e0+1)*132+d]=a0.y; wTg[(e0+2)*132+d]=a0.z; wTg[(e0+3)*132+d]=a0.w;
            wTg[(e0+4)*132+d]=a1.x; wTg[(e0+5)*132+d]=a1.y; wTg[(e0+6)*132+d]=a1.z; wTg[(e0+7)*132+d]=a1.w;
            wTn[(e0+0)*132+d]=b0.x; wTn[(e0+1)*132+d]=b0.y; wTn[(e0+2)*132+d]=b0.z; wTn[(e0+3)*132+d]=b0.w;
            wTn[(e0+4)*132+d]=b1.x; wTn[(e0+5)*132+d]=b1.y; wTn[(e0+6)*132+d]=b1.z; wTn[(e0+7)*132+d]=b1.w;
        }
        __syncthreads();

        #pragma unroll 8
        for (int d4 = 0; d4 < 32; ++d4) {
            floatx4 wgv = *reinterpret_cast<const floatx4*>(&wTg[og * 132 + d4 * 4]);
            floatx4 wnv = *reinterpret_cast<const floatx4*>(&wTn[og * 132 + d4 * 4]);
            #pragma unroll
            for (int rr = 0; rr < 2; ++rr) {
                floatx4 xv = *reinterpret_cast<const floatx4*>(&xs[(rg * 2 + rr) * 132 + d4 * 4]);
                accg4[rr] += xv * wgv;
                accn4[rr] += xv * wnv;
            }
        }
    }

    #pragma unroll
    for (int rr = 0; rr < 2; ++rr) {
        const int row = row0 + rg * 2 + rr;
        float accg = accg4[rr][0] + accg4[rr][1] + accg4[rr][2] + accg4[rr][3];
        float accn = accn4[rr][0] + accn4[rr][1] + accn4[rr][2] + accn4[rr][3];

        // keep libcall-precision softplus: gate threshold flips are the risk
        float sp = fmaxf(accn, 0.f) + log1pf(expf(-fabsf(accn)));
        float stddev = sp + 0.01f;
        float nz = noise[(size_t)row * EEXP + og];
        float z = accg + nz * stddev;

        float m = z;
        #pragma unroll
        for (int mask = 8; mask >= 1; mask >>= 1)
            m = fmaxf(m, __shfl_xor(m, mask, 16));
        float ez = expf(z - m);
        float s = ez;
        #pragma unroll
        for (int mask = 8; mask >= 1; mask >>= 1)
            s += __shfl_xor(s, mask, 16);
        float logit = ez / s;

        float lsum = logit;
        #pragma unroll
        for (int mask = 8; mask >= 1; mask >>= 1)
            lsum += __shfl_xor(lsum, mask, 16);
        float mean = lsum * (1.0f / 16.0f) - 1e-8f;

        float gate = (logit >= mean) ? logit : 0.0f;
        float denom = gate;
        #pragma unroll
        for (int mask = 8; mask >= 1; mask >>= 1)
            denom += __shfl_xor(denom, mask, 16);

        gates[(size_t)row * EEXP + og] = gate / denom;

        if (gate > 0.0f) {
            u32 p = atomicAdd(&lcnt[og], 1u);
            lrows[og * 32 + p] = (ushort)(rg * 2 + rr);
        } else {
            u32 p = atomicAdd(&izn, 1u);
            izlist[p] = (ushort)((rg * 2 + rr) * 16 + og);
        }
    }

    __syncthreads();
    if (t < 16) lbase[t] = atomicAdd(&cnt[t], lcnt[t]);

    // Coalesced zero-fill: 16 consecutive threads per inactive slot write one
    // contiguous 256-B segment (16 x float4).
    {
        const u32 ni = izn;
        const int grp = t >> 4, l16 = t & 15;
        float4* o4 = reinterpret_cast<float4*>(out);
        const float4 zf = {0.f, 0.f, 0.f, 0.f};
        for (u32 i = grp; i < ni; i += 16) {
            int slot = izlist[i];
            int rl = slot >> 4, e = slot & 15;
            o4[(size_t)(row0 + rl) * 256 + e * 16 + l16] = zf;
        }
    }

    __syncthreads();
    for (int i = t; i < 16 * 32; i += 256) {
        int e = i >> 5, j = i & 31;
        if ((u32)j < lcnt[e])
            rowlist[(size_t)e * BROWS + lbase[e] + j] = row0 + lrows[e * 32 + j];
    }
}

// ---------------------------------------------------------------------------
// Sparse expert MLP, BM=64, 40 KB LDS -> 4 blocks/CU (proven-best structure,
// byte-for-byte the R0/R3 kernel). Block (e,t) processes rowlist[e][t*64..).
// e = bx&15 pins each expert's W1T slice to one XCD's L2.
// ---------------------------------------------------------------------------
__global__ __launch_bounds__(256, 4) void expert_kernel(
    const ushort* __restrict__ xbf,    // [B][D] bf16, swizzled
    const float*  __restrict__ gates,  // [B][E]
    const ushort* __restrict__ W1T,    // [E][H][D] bf16, swizzled
    const float*  __restrict__ b1,     // [E][H]
    const ushort* __restrict__ W2T,    // [E][L][H] bf16, linear
    const float*  __restrict__ b2,     // [E][L]
    const u32*    __restrict__ cnt,    // [E]
    const u32*    __restrict__ rowlist,// [E][B]
    float* __restrict__ out)           // [B][E][L]
{
    __shared__ __align__(16) ushort lds[20480];  // A [0,8K)B, B [8K,40K)B; h [0,32K)B

    const int bx = blockIdx.x;
    const int e  = bx & 15;
    const int t  = bx >> 4;

    const int count = (int)cnt[e];
    if (t * BM >= count) return;
    const int nrt = min(BM, count - t * BM);
    const u32* rl = rowlist + (size_t)e * BROWS + t * BM;

    const int tid  = threadIdx.x;
    const int lane = tid & 63;
    const int wave = tid >> 6;

    const int lr = lane & 15;
    const int q  = lane >> 4;
    const int kq = q * 8;
    const int rq = q * 4;
    const int la = lane >> 3, lb = lane & 7;  // staging lane split

    const char* xg = (const char*)xbf;
    const char* w1 = (const char*)W1T + (size_t)e * HDIM * 1024;

    // Per-lane gathered A-row bases + swizzle re-key terms
    size_t abase[2]; int sxr[2];
    #pragma unroll
    for (int p = 0; p < 2; ++p) {
        int r  = wave * 16 + p * 8 + la;
        int rc = min(r, nrt - 1);
        u32 ri = rl[rc];
        abase[p] = (size_t)ri * 1024;
        sxr[p]   = (la ^ (int)(ri & 7)) << 4;
    }

    floatx4 acc[4][4] = {};

    for (int kb = 0; kb < 8; ++kb) {
        const int koff = kb * 128;   // byte offset within 1024-B row
        #pragma unroll
        for (int p = 0; p < 2; ++p) {   // A tile: 8 KB (gathered rows)
            int c = wave * 2 + p;
            gl_lds16(xg + abase[p] + koff + ((lb << 4) ^ sxr[p]), &lds[c * 512]);
        }
        #pragma unroll
        for (int p = 0; p < 8; ++p) {   // B tile: 32 KB (sequential W1T rows)
            int c = wave * 8 + p;
            gl_lds16(w1 + (size_t)(c * 8 + la) * 1024 + koff + (lb << 4),
                     &lds[4096 + c * 512]);
        }
        __syncthreads();

        #pragma unroll
        for (int s = 0; s < 2; ++s) {
            const int g = s * 4 + q;
            bf16x8 af[4], bfr[4];
            #pragma unroll
            for (int i = 0; i < 4; ++i) {
                int r = i * 16 + lr;
                af[i] = *reinterpret_cast<const bf16x8*>(&lds[r * 64 + ((g ^ (r & 7)) << 3)]);
            }
            #pragma unroll
            for (int j = 0; j < 4; ++j) {
                int r = wave * 64 + j * 16 + lr;
                bfr[j] = *reinterpret_cast<const bf16x8*>(&lds[4096 + r * 64 + ((g ^ (r & 7)) << 3)]);
            }
            #pragma unroll
            for (int i = 0; i < 4; ++i)
                #pragma unroll
                for (int j = 0; j < 4; ++j)
                    acc[i][j] = __builtin_amdgcn_mfma_f32_16x16x32_bf16(
                        af[i], bfr[j], acc[i][j], 0, 0, 0);
        }
        __syncthreads();
    }

    // h = fast_tanh(acc + b1) -> bf16, swizzled [64][256] at lds[0..32K)
    float b1v[4];
    #pragma unroll
    for (int j = 0; j < 4; ++j)
        b1v[j] = b1[e * HDIM + wave * 64 + j * 16 + lr];

    #pragma unroll
    for (int i = 0; i < 4; ++i)
        #pragma unroll
        for (int j = 0; j < 4; ++j) {
            int c = wave * 64 + j * 16 + lr;
            int gg = c >> 3;
            #pragma unroll
            for (int rr = 0; rr < 4; ++rr) {
                int r = i * 16 + rq + rr;
                float v = fast_tanh(acc[i][j][rr] + b1v[j]);
                lds[r * 256 + (((gg & 24) | ((gg & 7) ^ (r & 7))) << 3) + (c & 7)] = f2bf(v);
            }
        }
    __syncthreads();

    // Phase B: y[64][64]; wave owns rows [wave*16,+16); W2 frags from global
    const ushort* w2 = W2T + (size_t)e * LDIM * HDIM;
    floatx4 acc2[4] = {};
    #pragma unroll
    for (int s = 0; s < 8; ++s) {
        int r = wave * 16 + lr;
        int g = s * 4 + q;
        bf16x8 af = *reinterpret_cast<const bf16x8*>(
            &lds[r * 256 + (((g & 24) | ((g & 7) ^ (r & 7))) << 3)]);
        #pragma unroll
        for (int j = 0; j < 4; ++j) {
            bf16x8 bfr = *reinterpret_cast<const bf16x8*>(
                &w2[(size_t)(j * 16 + lr) * HDIM + s * 32 + kq]);
            acc2[j] = __builtin_amdgcn_mfma_f32_16x16x32_bf16(af, bfr, acc2[j], 0, 0, 0);
        }
    }

    float b2v[4];
    #pragma unroll
    for (int j = 0; j < 4; ++j)
        b2v[j] = b2[e * LDIM + j * 16 + lr];

    #pragma unroll
    for (int rr = 0; rr < 4; ++rr) {
        int r  = wave * 16 + rq + rr;
        int rc = min(r, nrt - 1);
        u32 ri = rl[rc];
        float gsc = gates[(size_t)ri * EEXP + e];
        if (r < nrt) {
            #pragma unroll
            for (int j = 0; j < 4; ++j)
                out[(size_t)ri * (EEXP * LDIM) + e * LDIM + j * 16 + lr] =
                    (acc2[j][rr] + b2v[j]) * gsc;
        }
    }
}

// ---------------------------------------------------------------------------
extern "C" void kernel_launch(void* const* d_in, const int* in_sizes, int n_in,
                              void* d_out, int out_size, void* d_ws, size_t ws_size,
                              hipStream_t stream) {
    (void)in_sizes; (void)n_in; (void)out_size; (void)ws_size;
    const float* x     = (const float*)d_in[0];
    const float* noise = (const float*)d_in[1];
    const float* wg    = (const float*)d_in[2];
    const float* wn    = (const float*)d_in[3];
    const float* W1    = (const float*)d_in[4];
    const float* b1    = (const float*)d_in[5];
    const float* W2    = (const float*)d_in[6];
    const float* b2    = (const float*)d_in[7];
    float* out = (float*)d_out;

    char* ws = (char*)d_ws;
    float*  gates   = (float*)ws;                          // 1 MiB
    ushort* W1T     = (ushort*)(ws + (1 << 20));           // 4 MiB
    ushort* W2T     = (ushort*)(ws + (5 << 20));           // 0.5 MiB
    ushort* xbf     = (ushort*)(ws + (6 << 20));           // 16 MiB
    u32*    cnt     = (u32*)(ws + (22 << 20));             // 64 B
    u32*    rowlist = (u32*)(ws + (24 << 20));             // 1 MiB

    hipMemsetAsync(cnt, 0, EEXP * sizeof(u32), stream);
    gate_aux_kernel<<<512 + 2304, 256, 0, stream>>>(
        x, noise, wg, wn, W1, W2, gates, xbf, W1T, W2T, cnt, rowlist, out);
    expert_kernel<<<(BROWS / BM) * EEXP, 256, 0, stream>>>(
        xbf, gates, W1T, b1, W2T, b2, cnt, rowlist, out);
}

// Round 7
// 171.661 us; speedup vs baseline: 1.2317x; 1.0016x over previous
//
#include <hip/hip_runtime.h>
#include <stdint.h>

#define BROWS 16384
#define DDIM  512
#define EEXP  16
#define HDIM  256
#define LDIM  64
#define BM    64

typedef __bf16  bf16x8  __attribute__((ext_vector_type(8)));
typedef float   floatx4 __attribute__((ext_vector_type(4)));
typedef ushort  ushort8 __attribute__((ext_vector_type(8)));
typedef unsigned int u32;

__device__ __forceinline__ ushort f2bf(float f) {
    uint32_t u = __builtin_bit_cast(uint32_t, f);
    u += 0x7fffu + ((u >> 16) & 1u);   // RNE
    return (ushort)(u >> 16);
}

// tanh(x) = 1 - 2/(exp2(2x*log2e)+1); saturates correctly, rel err ~1e-6.
__device__ __forceinline__ float fast_tanh(float x) {
    float e = __builtin_amdgcn_exp2f(x * 2.8853900817779268f);
    return 1.0f - 2.0f * __builtin_amdgcn_rcpf(e + 1.0f);
}

__device__ __forceinline__ void gl_lds16(const void* g, void* l) {
    __builtin_amdgcn_global_load_lds(
        (const __attribute__((address_space(1))) u32*)g,
        (__attribute__((address_space(3))) u32*)l, 16, 0, 0);
}

// ---------------------------------------------------------------------------
// MERGED kernel. Blocks 0..511: gating with T14 async-staged DOUBLE-BUFFERED
// chunks (issue chunk k+1's global loads before the barrier; 1 barrier/chunk
// instead of 2) + fused x->bf16 swizzled cvt + atomic rowlist + coalesced
// zero-fill. Blocks 512..1087: W1/W2 transpose as 64x64 tiles with float4
// loads and ushort4 swizzle-preserving stores (vs 32x32 scalar-store tiles).
// ---------------------------------------------------------------------------
__global__ __launch_bounds__(256) void gate_aux_kernel(
    const float* __restrict__ x,      // [B][D]
    const float* __restrict__ noise,  // [B][E]
    const float* __restrict__ wg,     // [D][E]
    const float* __restrict__ wn,     // [D][E]
    const float* __restrict__ W1,     // [E][D][H]
    const float* __restrict__ W2,     // [E][H][L]
    float* __restrict__ gates,        // [B][E]
    ushort* __restrict__ xbf,         // [B][D] bf16 swizzled
    ushort* __restrict__ W1T,         // [E][H][D] bf16 swizzled
    ushort* __restrict__ W2T,         // [E][L][H] bf16 linear
    u32* __restrict__ cnt,            // [E] (pre-zeroed)
    u32* __restrict__ rowlist,        // [E][B] unsorted-compact
    float* __restrict__ out)          // [B][E][L]
{
    // Big LDS region, unioned between gating (xs/wT double buffers) and
    // transpose (64x68 f32 tile).
    __shared__ __align__(16) float smbig[16896];   // 66 KB
    __shared__ u32 lcnt[16];
    __shared__ u32 lbase[16];
    __shared__ ushort lrows[16 * 32];
    __shared__ u32 izn;
    __shared__ ushort izlist[512];

    if (blockIdx.x >= 512) {
        // ---- transpose path: 64x64 tiles ----
        float (*tile)[68] = reinterpret_cast<float(*)[68]>(smbig);
        int b = blockIdx.x - 512;
        const float* src; ushort* dst; int R, C, c0, r0, swz, ei;
        if (b < 512) {                     // W1: [512][256] -> [256][512] swz
            ei = b >> 5; int rem = b & 31;
            r0 = (rem >> 2) * 64; c0 = (rem & 3) * 64;
            R = DDIM; C = HDIM; swz = 1;
            src = W1; dst = W1T;
        } else {                           // W2: [256][64] -> [64][256]
            b -= 512;
            ei = b >> 2; int rem = b & 3;
            r0 = rem * 64; c0 = 0;
            R = HDIM; C = LDIM; swz = 0;
            src = W2; dst = W2T;
        }
        const int tr  = threadIdx.x >> 2;        // 0..63 source row
        const int tc4 = threadIdx.x & 3;         // 4 col-slots of 16

        const float* s = src + (size_t)ei * R * C + (size_t)(r0 + tr) * C + c0 + tc4 * 16;
        #pragma unroll
        for (int i = 0; i < 4; ++i) {
            float4 v = *reinterpret_cast<const float4*>(s + i * 4);
            *reinterpret_cast<float4*>(&tile[tr][tc4 * 16 + i * 4]) = v;
        }
        __syncthreads();

        ushort* d = dst + (size_t)ei * R * C;
        const int hh = c0 + tr;                  // output row (C-dim)
        #pragma unroll
        for (int i = 0; i < 4; ++i) {
            int rrb  = tc4 * 16 + i * 4;         // tile row = source-row offset
            int colb = r0 + rrb;                 // output col (R-dim)
            int col2 = colb;
            if (swz) {
                int g = (colb >> 3) & 7;
                col2 = (colb & ~63) | ((g ^ (hh & 7)) << 3) | (colb & 7);
            }
            ushort4 o;
            o.x = f2bf(tile[rrb + 0][tr]);
            o.y = f2bf(tile[rrb + 1][tr]);
            o.z = f2bf(tile[rrb + 2][tr]);
            o.w = f2bf(tile[rrb + 3][tr]);
            *reinterpret_cast<ushort4*>(&d[(size_t)hh * R + col2]) = o;
        }
        return;
    }

    // ---- gating path ----
    float* xs  = smbig;                  // [2][32*132]
    float* wtg = smbig + 2 * 32 * 132;   // [2][16*132]
    float* wtn = wtg   + 2 * 16 * 132;   // [2][16*132]

    const int t    = threadIdx.x;
    const int blk  = blockIdx.x;
    const int row0 = blk * 32;
    const int og   = t & 15, rg = t >> 4;
    const int sr   = t >> 3, sc = (t & 7) * 16;   // x-stage row/col
    const int sd   = t >> 1, se = (t & 1) * 8;    // w-stage d/e0

    if (t < 16) lcnt[t] = 0;
    if (t == 0) izn = 0;

    float4 xf0, xf1, xf2, xf3, wg0, wg1, wn0, wn1;
    const float* srcx0 = &x[(size_t)(row0 + sr) * DDIM + sc];

    // issue chunk-0 loads
    {
        const float4* p = reinterpret_cast<const float4*>(srcx0);
        xf0 = p[0]; xf1 = p[1]; xf2 = p[2]; xf3 = p[3];
        const float4* pg = reinterpret_cast<const float4*>(&wg[(size_t)sd * EEXP + se]);
        const float4* pn = reinterpret_cast<const float4*>(&wn[(size_t)sd * EEXP + se]);
        wg0 = pg[0]; wg1 = pg[1]; wn0 = pn[0]; wn1 = pn[1];
    }

    floatx4 accg4[2] = {}, accn4[2] = {};

    for (int ch = 0; ch < 4; ++ch) {
        const int k0  = ch * 128;
        const int buf = ch & 1;
        float* xsb = xs  + buf * (32 * 132);
        float* wgl = wtg + buf * (16 * 132);
        float* wnl = wtn + buf * (16 * 132);

        {   // LDS writes + xbf writeback (from regs loaded last iteration)
            float* dstx = &xsb[sr * 132 + sc];
            reinterpret_cast<float4*>(dstx)[0] = xf0;
            reinterpret_cast<float4*>(dstx)[1] = xf1;
            reinterpret_cast<float4*>(dstx)[2] = xf2;
            reinterpret_cast<float4*>(dstx)[3] = xf3;

            const int row = row0 + sr;
            const int sw  = sr & 7;
            #pragma unroll
            for (int i = 0; i < 2; ++i) {
                int cb = k0 + sc + i * 8;
                int kb = cb >> 6;
                int g  = (cb >> 3) & 7;
                int gp = g ^ sw;
                float4 a = (i == 0) ? xf0 : xf2;
                float4 b = (i == 0) ? xf1 : xf3;
                ushort8 t8;
                t8[0]=f2bf(a.x); t8[1]=f2bf(a.y); t8[2]=f2bf(a.z); t8[3]=f2bf(a.w);
                t8[4]=f2bf(b.x); t8[5]=f2bf(b.y); t8[6]=f2bf(b.z); t8[7]=f2bf(b.w);
                *reinterpret_cast<ushort8*>(&xbf[(size_t)row * DDIM + kb * 64 + gp * 8]) = t8;
            }

            wgl[(se+0)*132+sd]=wg0.x; wgl[(se+1)*132+sd]=wg0.y; wgl[(se+2)*132+sd]=wg0.z; wgl[(se+3)*132+sd]=wg0.w;
            wgl[(se+4)*132+sd]=wg1.x; wgl[(se+5)*132+sd]=wg1.y; wgl[(se+6)*132+sd]=wg1.z; wgl[(se+7)*132+sd]=wg1.w;
            wnl[(se+0)*132+sd]=wn0.x; wnl[(se+1)*132+sd]=wn0.y; wnl[(se+2)*132+sd]=wn0.z; wnl[(se+3)*132+sd]=wn0.w;
            wnl[(se+4)*132+sd]=wn1.x; wnl[(se+5)*132+sd]=wn1.y; wnl[(se+6)*132+sd]=wn1.z; wnl[(se+7)*132+sd]=wn1.w;
        }

        if (ch < 3) {   // issue next chunk's loads; land during barrier+compute
            const int k1 = k0 + 128;
            const float4* p = reinterpret_cast<const float4*>(srcx0 + k1);
            xf0 = p[0]; xf1 = p[1]; xf2 = p[2]; xf3 = p[3];
            const float4* pg = reinterpret_cast<const float4*>(&wg[(size_t)(k1 + sd) * EEXP + se]);
            const float4* pn = reinterpret_cast<const float4*>(&wn[(size_t)(k1 + sd) * EEXP + se]);
            wg0 = pg[0]; wg1 = pg[1]; wn0 = pn[0]; wn1 = pn[1];
        }

        __syncthreads();   // single barrier/chunk: writes target buf, next
                           // iteration writes buf^1, so no trailing barrier

        #pragma unroll 8
        for (int d4 = 0; d4 < 32; ++d4) {
            floatx4 wgv = *reinterpret_cast<const floatx4*>(&wgl[og * 132 + d4 * 4]);
            floatx4 wnv = *reinterpret_cast<const floatx4*>(&wnl[og * 132 + d4 * 4]);
            #pragma unroll
            for (int rr = 0; rr < 2; ++rr) {
                floatx4 xv = *reinterpret_cast<const floatx4*>(&xsb[(rg * 2 + rr) * 132 + d4 * 4]);
                accg4[rr] += xv * wgv;
                accn4[rr] += xv * wnv;
            }
        }
    }

    #pragma unroll
    for (int rr = 0; rr < 2; ++rr) {
        const int row = row0 + rg * 2 + rr;
        float accg = accg4[rr][0] + accg4[rr][1] + accg4[rr][2] + accg4[rr][3];
        float accn = accn4[rr][0] + accn4[rr][1] + accn4[rr][2] + accn4[rr][3];

        // keep libcall-precision softplus: gate threshold flips are the risk
        float sp = fmaxf(accn, 0.f) + log1pf(expf(-fabsf(accn)));
        float stddev = sp + 0.01f;
        float nz = noise[(size_t)row * EEXP + og];
        float z = accg + nz * stddev;

        float m = z;
        #pragma unroll
        for (int mask = 8; mask >= 1; mask >>= 1)
            m = fmaxf(m, __shfl_xor(m, mask, 16));
        float ez = expf(z - m);
        float s = ez;
        #pragma unroll
        for (int mask = 8; mask >= 1; mask >>= 1)
            s += __shfl_xor(s, mask, 16);
        float logit = ez / s;

        float lsum = logit;
        #pragma unroll
        for (int mask = 8; mask >= 1; mask >>= 1)
            lsum += __shfl_xor(lsum, mask, 16);
        float mean = lsum * (1.0f / 16.0f) - 1e-8f;

        float gate = (logit >= mean) ? logit : 0.0f;
        float denom = gate;
        #pragma unroll
        for (int mask = 8; mask >= 1; mask >>= 1)
            denom += __shfl_xor(denom, mask, 16);

        gates[(size_t)row * EEXP + og] = gate / denom;

        if (gate > 0.0f) {
            u32 p = atomicAdd(&lcnt[og], 1u);
            lrows[og * 32 + p] = (ushort)(rg * 2 + rr);
        } else {
            u32 p = atomicAdd(&izn, 1u);
            izlist[p] = (ushort)((rg * 2 + rr) * 16 + og);
        }
    }

    __syncthreads();
    if (t < 16) lbase[t] = atomicAdd(&cnt[t], lcnt[t]);

    // Coalesced zero-fill: 16 consecutive threads per inactive slot write one
    // contiguous 256-B segment (16 x float4).
    {
        const u32 ni = izn;
        const int grp = t >> 4, l16 = t & 15;
        float4* o4 = reinterpret_cast<float4*>(out);
        const float4 zf = {0.f, 0.f, 0.f, 0.f};
        for (u32 i = grp; i < ni; i += 16) {
            int slot = izlist[i];
            int rl = slot >> 4, e = slot & 15;
            o4[(size_t)(row0 + rl) * 256 + e * 16 + l16] = zf;
        }
    }

    __syncthreads();
    for (int i = t; i < 16 * 32; i += 256) {
        int e = i >> 5, j = i & 31;
        if ((u32)j < lcnt[e])
            rowlist[(size_t)e * BROWS + lbase[e] + j] = row0 + lrows[e * 32 + j];
    }
}

// ---------------------------------------------------------------------------
// Sparse expert MLP, BM=64, 40 KB LDS -> 4 blocks/CU (proven-best structure,
// byte-for-byte the R0/R3/R6 kernel). Block (e,t) processes rowlist[e][t*64..).
// e = bx&15 pins each expert's W1T slice to one XCD's L2.
// ---------------------------------------------------------------------------
__global__ __launch_bounds__(256, 4) void expert_kernel(
    const ushort* __restrict__ xbf,    // [B][D] bf16, swizzled
    const float*  __restrict__ gates,  // [B][E]
    const ushort* __restrict__ W1T,    // [E][H][D] bf16, swizzled
    const float*  __restrict__ b1,     // [E][H]
    const ushort* __restrict__ W2T,    // [E][L][H] bf16, linear
    const float*  __restrict__ b2,     // [E][L]
    const u32*    __restrict__ cnt,    // [E]
    const u32*    __restrict__ rowlist,// [E][B]
    float* __restrict__ out)           // [B][E][L]
{
    __shared__ __align__(16) ushort lds[20480];  // A [0,8K)B, B [8K,40K)B; h [0,32K)B

    const int bx = blockIdx.x;
    const int e  = bx & 15;
    const int t  = bx >> 4;

    const int count = (int)cnt[e];
    if (t * BM >= count) return;
    const int nrt = min(BM, count - t * BM);
    const u32* rl = rowlist + (size_t)e * BROWS + t * BM;

    const int tid  = threadIdx.x;
    const int lane = tid & 63;
    const int wave = tid >> 6;

    const int lr = lane & 15;
    const int q  = lane >> 4;
    const int kq = q * 8;
    const int rq = q * 4;
    const int la = lane >> 3, lb = lane & 7;  // staging lane split

    const char* xg = (const char*)xbf;
    const char* w1 = (const char*)W1T + (size_t)e * HDIM * 1024;

    // Per-lane gathered A-row bases + swizzle re-key terms
    size_t abase[2]; int sxr[2];
    #pragma unroll
    for (int p = 0; p < 2; ++p) {
        int r  = wave * 16 + p * 8 + la;
        int rc = min(r, nrt - 1);
        u32 ri = rl[rc];
        abase[p] = (size_t)ri * 1024;
        sxr[p]   = (la ^ (int)(ri & 7)) << 4;
    }

    floatx4 acc[4][4] = {};

    for (int kb = 0; kb < 8; ++kb) {
        const int koff = kb * 128;   // byte offset within 1024-B row
        #pragma unroll
        for (int p = 0; p < 2; ++p) {   // A tile: 8 KB (gathered rows)
            int c = wave * 2 + p;
            gl_lds16(xg + abase[p] + koff + ((lb << 4) ^ sxr[p]), &lds[c * 512]);
        }
        #pragma unroll
        for (int p = 0; p < 8; ++p) {   // B tile: 32 KB (sequential W1T rows)
            int c = wave * 8 + p;
            gl_lds16(w1 + (size_t)(c * 8 + la) * 1024 + koff + (lb << 4),
                     &lds[4096 + c * 512]);
        }
        __syncthreads();

        #pragma unroll
        for (int s = 0; s < 2; ++s) {
            const int g = s * 4 + q;
            bf16x8 af[4], bfr[4];
            #pragma unroll
            for (int i = 0; i < 4; ++i) {
                int r = i * 16 + lr;
                af[i] = *reinterpret_cast<const bf16x8*>(&lds[r * 64 + ((g ^ (r & 7)) << 3)]);
            }
            #pragma unroll
            for (int j = 0; j < 4; ++j) {
                int r = wave * 64 + j * 16 + lr;
                bfr[j] = *reinterpret_cast<const bf16x8*>(&lds[4096 + r * 64 + ((g ^ (r & 7)) << 3)]);
            }
            #pragma unroll
            for (int i = 0; i < 4; ++i)
                #pragma unroll
                for (int j = 0; j < 4; ++j)
                    acc[i][j] = __builtin_amdgcn_mfma_f32_16x16x32_bf16(
                        af[i], bfr[j], acc[i][j], 0, 0, 0);
        }
        __syncthreads();
    }

    // h = fast_tanh(acc + b1) -> bf16, swizzled [64][256] at lds[0..32K)
    float b1v[4];
    #pragma unroll
    for (int j = 0; j < 4; ++j)
        b1v[j] = b1[e * HDIM + wave * 64 + j * 16 + lr];

    #pragma unroll
    for (int i = 0; i < 4; ++i)
        #pragma unroll
        for (int j = 0; j < 4; ++j) {
            int c = wave * 64 + j * 16 + lr;
            int gg = c >> 3;
            #pragma unroll
            for (int rr = 0; rr < 4; ++rr) {
                int r = i * 16 + rq + rr;
                float v = fast_tanh(acc[i][j][rr] + b1v[j]);
                lds[r * 256 + (((gg & 24) | ((gg & 7) ^ (r & 7))) << 3) + (c & 7)] = f2bf(v);
            }
        }
    __syncthreads();

    // Phase B: y[64][64]; wave owns rows [wave*16,+16); W2 frags from global
    const ushort* w2 = W2T + (size_t)e * LDIM * HDIM;
    floatx4 acc2[4] = {};
    #pragma unroll
    for (int s = 0; s < 8; ++s) {
        int r = wave * 16 + lr;
        int g = s * 4 + q;
        bf16x8 af = *reinterpret_cast<const bf16x8*>(
            &lds[r * 256 + (((g & 24) | ((g & 7) ^ (r & 7))) << 3)]);
        #pragma unroll
        for (int j = 0; j < 4; ++j) {
            bf16x8 bfr = *reinterpret_cast<const bf16x8*>(
                &w2[(size_t)(j * 16 + lr) * HDIM + s * 32 + kq]);
            acc2[j] = __builtin_amdgcn_mfma_f32_16x16x32_bf16(af, bfr, acc2[j], 0, 0, 0);
        }
    }

    float b2v[4];
    #pragma unroll
    for (int j = 0; j < 4; ++j)
        b2v[j] = b2[e * LDIM + j * 16 + lr];

    #pragma unroll
    for (int rr = 0; rr < 4; ++rr) {
        int r  = wave * 16 + rq + rr;
        int rc = min(r, nrt - 1);
        u32 ri = rl[rc];
        float gsc = gates[(size_t)ri * EEXP + e];
        if (r < nrt) {
            #pragma unroll
            for (int j = 0; j < 4; ++j)
                out[(size_t)ri * (EEXP * LDIM) + e * LDIM + j * 16 + lr] =
                    (acc2[j][rr] + b2v[j]) * gsc;
        }
    }
}

// ---------------------------------------------------------------------------
extern "C" void kernel_launch(void* const* d_in, const int* in_sizes, int n_in,
                              void* d_out, int out_size, void* d_ws, size_t ws_size,
                              hipStream_t stream) {
    (void)in_sizes; (void)n_in; (void)out_size; (void)ws_size;
    const float* x     = (const float*)d_in[0];
    const float* noise = (const float*)d_in[1];
    const float* wg    = (const float*)d_in[2];
    const float* wn    = (const float*)d_in[3];
    const float* W1    = (const float*)d_in[4];
    const float* b1    = (const float*)d_in[5];
    const float* W2    = (const float*)d_in[6];
    const float* b2    = (const float*)d_in[7];
    float* out = (float*)d_out;

    char* ws = (char*)d_ws;
    float*  gates   = (float*)ws;                          // 1 MiB
    ushort* W1T     = (ushort*)(ws + (1 << 20));           // 4 MiB
    ushort* W2T     = (ushort*)(ws + (5 << 20));           // 0.5 MiB
    ushort* xbf     = (ushort*)(ws + (6 << 20));           // 16 MiB
    u32*    cnt     = (u32*)(ws + (22 << 20));             // 64 B
    u32*    rowlist = (u32*)(ws + (24 << 20));             // 1 MiB

    hipMemsetAsync(cnt, 0, EEXP * sizeof(u32), stream);
    gate_aux_kernel<<<512 + 576, 256, 0, stream>>>(
        x, noise, wg, wn, W1, W2, gates, xbf, W1T, W2T, cnt, rowlist, out);
    expert_kernel<<<(BROWS / BM) * EEXP, 256, 0, stream>>>(
        xbf, gates, W1T, b1, W2T, b2, cnt, rowlist, out);
}